// Round 5
// baseline (150.802 us; speedup 1.0000x reference)
//
#include <hip/hip_runtime.h>
#include <math.h>

// Problem constants
#define NIN   1535
#define NN    1536
#define BB    32
#define BN_EPS 1e-5f
#define CH    64               // rows per chunk
#define NCH   24               // chunks per batch
#define NBLK  (BB * NCH)       // 768 = 3 * 256 exactly (no tail block-wave)

// Workspace layout (floats): M[768], S[768], vec[768][64]
#define WS_M    0
#define WS_S    768
#define WS_V    1536

__device__ __forceinline__ float rdlane(float v, int l) {
  return __int_as_float(__builtin_amdgcn_readlane(__float_as_int(v), l));
}

// ================================================================ k_main
// 768 blocks: encode one 64-row chunk (fc1+relu, fc2+relu; output node uses
// the enc layer), per-row score sk = h2·u (q-side score term is constant
// over the softmax axis and cancels; so does bK·wQKk), online-softmax
// partial (m, sum_e, sum_e*h2) in registers per wave, 4-wave combine.
// W2 rows in VGPRs; h1 broadcast via v_readlane (VALU pipe, not LDS).
__global__ __launch_bounds__(256) void k_main(
    const float* __restrict__ xx, const float* __restrict__ yy,
    const float* __restrict__ oxx,
    const float* __restrict__ W1, const float* __restrict__ b1,
    const float* __restrict__ W2, const float* __restrict__ b2,
    const float* __restrict__ Wenc, const float* __restrict__ benc,
    const float* __restrict__ WK, const float* __restrict__ wQKk,
    float* __restrict__ ws) {
  __shared__ float xs[512];            // [64 rows][8]
  __shared__ float ys[64];
  __shared__ float up[4][64];          // per-wave u partials
  __shared__ float cm[4], cs[4];       // per-wave online-softmax m, s
  __shared__ float cvec[4][64];        // per-wave sum_e*h2

  const int t = threadIdx.x;
  const int blk = blockIdx.x;
  const int b = blk & 31;
  const int c = blk >> 5;
  const int pp = b * NCH + c;
  const int w = t >> 6, lane = t & 63;

  // ---- stage inputs (coalesced) ----
  for (int e = t; e < 512; e += 256) {
    int j = e >> 3, k = e & 7;
    int r0 = c * CH + j;
    xs[e] = (r0 < NIN) ? xx[((size_t)b * NIN + r0) * 8 + k] : oxx[b * 8 + k];
  }
  if (t < 64) {
    int r0 = c * CH + t;
    ys[t] = (r0 < NIN) ? yy[b * NIN + r0] : 0.f;
  }
  // u = WK^T @ wQKk, coalesced: wave w sums rows [w*16, w*16+16)
  {
    float part = 0.f;
    #pragma unroll
    for (int g = 0; g < 16; g++) {
      int h0 = w * 16 + g;
      part += wQKk[h0] * WK[h0 * 64 + lane];  // lane = column -> coalesced
    }
    up[w][lane] = part;
  }
  __syncthreads();
  const float uv = up[0][lane] + up[1][lane] + up[2][lane] + up[3][lane];

  // ---- per-lane register-resident weights ----
  float w2r[64];                       // W2 row `lane` (its fc2 column)
  {
    const float4* wr = (const float4*)(W2 + lane * 64);
    #pragma unroll
    for (int q = 0; q < 16; q++) {
      float4 v = wr[q];
      w2r[4 * q] = v.x; w2r[4 * q + 1] = v.y;
      w2r[4 * q + 2] = v.z; w2r[4 * q + 3] = v.w;
    }
  }
  float w1r[9];
  #pragma unroll
  for (int i = 0; i < 9; i++) w1r[i] = W1[lane * 9 + i];
  const float b1v = b1[lane], b2v = b2[lane];

  // ---- 16 rows per wave, online softmax in registers ----
  float m_run = -1e30f, s_run = 0.f, acc_v = 0.f;
  for (int rr = 0; rr < 16; rr++) {
    int j = w * 16 + rr;
    int r0 = c * CH + j;
    float4 x0 = *(const float4*)(xs + j * 8);     // broadcast reads
    float4 x1 = *(const float4*)(xs + j * 8 + 4);
    float h2;
    if (r0 < NIN) {                               // wave-uniform branch
      float a = b1v;
      a += x0.x * w1r[0] + x0.y * w1r[1] + x0.z * w1r[2] + x0.w * w1r[3];
      a += x1.x * w1r[4] + x1.y * w1r[5] + x1.z * w1r[6] + x1.w * w1r[7];
      a += ys[j] * w1r[8];
      float h1v = fmaxf(a, 0.f);
      float a0 = b2v, a1 = 0.f, a2 = 0.f, a3 = 0.f;
      #pragma unroll
      for (int k = 0; k < 64; k += 4) {           // h1 broadcast on VALU pipe
        a0 += rdlane(h1v, k)     * w2r[k];
        a1 += rdlane(h1v, k + 1) * w2r[k + 1];
        a2 += rdlane(h1v, k + 2) * w2r[k + 2];
        a3 += rdlane(h1v, k + 3) * w2r[k + 3];
      }
      h2 = fmaxf((a0 + a1) + (a2 + a3), 0.f);
    } else {                                      // output node: enc layer
      const float4* we = (const float4*)(Wenc + lane * 8);
      float4 w0 = we[0], w1v = we[1];
      float a = benc[lane];
      a += x0.x * w0.x + x0.y * w0.y + x0.z * w0.z + x0.w * w0.w;
      a += x1.x * w1v.x + x1.y * w1v.y + x1.z * w1v.z + x1.w * w1v.w;
      h2 = fmaxf(a, 0.f);
    }
    // score (butterfly: every lane gets the full dot)
    float p = h2 * uv;
    p += __shfl_xor(p, 1);  p += __shfl_xor(p, 2);  p += __shfl_xor(p, 4);
    p += __shfl_xor(p, 8);  p += __shfl_xor(p, 16); p += __shfl_xor(p, 32);
    // online softmax update
    float mn = fmaxf(m_run, p);
    float f  = __expf(m_run - mn);
    float e  = __expf(p - mn);
    s_run = s_run * f + e;
    acc_v = acc_v * f + e * h2;
    m_run = mn;
  }

  // ---- combine 4 waves, write chunk partial ----
  if (lane == 0) { cm[w] = m_run; cs[w] = s_run; }
  cvec[w][lane] = acc_v;
  __syncthreads();
  if (t < 64) {
    float M = fmaxf(fmaxf(cm[0], cm[1]), fmaxf(cm[2], cm[3]));
    float f0 = __expf(cm[0] - M), f1 = __expf(cm[1] - M);
    float f2 = __expf(cm[2] - M), f3 = __expf(cm[3] - M);
    ws[WS_V + pp * 64 + t] = f0 * cvec[0][t] + f1 * cvec[1][t] +
                             f2 * cvec[2][t] + f3 * cvec[3][t];
    if (t == 0) {
      ws[WS_M + pp] = M;
      ws[WS_S + pp] = f0 * cs[0] + f1 * cs[1] + f2 * cs[2] + f3 * cs[3];
    }
  }
}

// ================================================================ k_tail
// One block, 512 threads: fold WAVT = (WA@WV)^T + bAV, combine softmax
// partials, round-1 z = ss@WAV^T + bAV, rounds 2..4 (identical nodes ->
// uniform softmax is identity) + BN + relu, heads.
__global__ __launch_bounds__(512) void k_tail(
    const float* __restrict__ ws,
    const float* __restrict__ WV, const float* __restrict__ bV,
    const float* __restrict__ WA, const float* __restrict__ bA,
    const float* __restrict__ gamma, const float* __restrict__ beta,
    const float* __restrict__ Wmu, const float* __restrict__ bmu,
    const float* __restrict__ Wsig, const float* __restrict__ bsig,
    float* __restrict__ out) {
  __shared__ float WAVT[4096];     // WAVT[k][h]
  __shared__ float bAVs[64];
  __shared__ float Ml[768], Sl[768], wexp[768];
  __shared__ float Mb[32], iSb[32];
  __shared__ float st[32 * 66];    // stride 66 -> conflict-free
  __shared__ float zs[32 * 66];
  __shared__ float scs[64], shs[64];
  const int t = threadIdx.x;

  for (int p = t; p < 768; p += 512) {
    Ml[p] = ws[WS_M + p];
    Sl[p] = ws[WS_S + p];
  }
  // fold WAVT[k][h] = sum_m WA[h][m]*WV[m][k]; t -> (kg=t>>6 in 0..7, h)
  {
    int kg = t >> 6, h = t & 63;
    float acc[8];
    #pragma unroll
    for (int kk = 0; kk < 8; kk++) acc[kk] = 0.f;
    for (int m = 0; m < 64; m++) {
      float wa = WA[h * 64 + m];                    // L1-hot gather
      const float4* wv = (const float4*)(WV + m * 64 + kg * 8);  // uniform
      float4 w0 = wv[0], w1 = wv[1];
      acc[0] += wa * w0.x; acc[1] += wa * w0.y;
      acc[2] += wa * w0.z; acc[3] += wa * w0.w;
      acc[4] += wa * w1.x; acc[5] += wa * w1.y;
      acc[6] += wa * w1.z; acc[7] += wa * w1.w;
    }
    #pragma unroll
    for (int kk = 0; kk < 8; kk++) WAVT[(kg * 8 + kk) * 64 + h] = acc[kk];
  }
  if (t < 64) {                 // bAV = bA + WA@bV
    float a = bA[t];
    #pragma unroll
    for (int k = 0; k < 64; k++) a += WA[t * 64 + k] * bV[k];
    bAVs[t] = a;
  }
  __syncthreads();

  if (t < 32) {
    float m = -1e30f;
    for (int cc = 0; cc < NCH; cc++) m = fmaxf(m, Ml[t * NCH + cc]);
    Mb[t] = m;
  }
  __syncthreads();
  for (int p = t; p < 768; p += 512) wexp[p] = __expf(Ml[p] - Mb[p / NCH]);
  __syncthreads();
  if (t < 32) {
    float s = 0.f;
    for (int cc = 0; cc < NCH; cc++) {
      int p = t * NCH + cc;
      s += Sl[p] * wexp[p];
    }
    iSb[t] = 1.0f / s;
  }
  __syncthreads();
  {  // ss[b][h] = (sum_c wexp * vec_c[h]) / S_b ; t -> (bb=t>>4, hg=t&15)
    int bb = t >> 4, hg = t & 15;
    float acc[4];
    #pragma unroll
    for (int jj = 0; jj < 4; jj++) acc[jj] = 0.f;
    for (int cc = 0; cc < NCH; cc++) {
      int p = bb * NCH + cc;
      float wgt = wexp[p];
      const float* vp = ws + WS_V + p * 64 + hg;
      #pragma unroll
      for (int jj = 0; jj < 4; jj++) acc[jj] += wgt * vp[jj * 16];
    }
    float is = iSb[bb];
    #pragma unroll
    for (int jj = 0; jj < 4; jj++) st[bb * 66 + hg + 16 * jj] = acc[jj] * is;
  }
  __syncthreads();

  for (int r = 0; r < 4; r++) {
    {
      int bb = t >> 4, hg = t & 15;
      float acc[4];
      #pragma unroll
      for (int jj = 0; jj < 4; jj++) acc[jj] = bAVs[hg + 16 * jj];
      for (int k = 0; k < 64; k++) {
        float v = st[bb * 66 + k];
        const float* wp = WAVT + k * 64 + hg;
        #pragma unroll
        for (int jj = 0; jj < 4; jj++) acc[jj] += v * wp[16 * jj];
      }
      #pragma unroll
      for (int jj = 0; jj < 4; jj++) zs[bb * 66 + hg + 16 * jj] = acc[jj];
    }
    __syncthreads();
    if (t < 64) {
      float s1 = 0.f;
      for (int bb2 = 0; bb2 < BB; bb2++) s1 += zs[bb2 * 66 + t];
      float mu = s1 * (1.0f / BB);
      float s2 = 0.f;
      for (int bb2 = 0; bb2 < BB; bb2++) {
        float d = zs[bb2 * 66 + t] - mu;
        s2 += d * d;
      }
      float inv = gamma[t] / sqrtf(s2 * (1.0f / BB) + BN_EPS);
      scs[t] = inv;
      shs[t] = beta[t] - mu * inv;
    }
    __syncthreads();
    for (int e = t; e < BB * 64; e += 512) {
      int bb2 = e >> 6, hh = e & 63;
      st[bb2 * 66 + hh] = fmaxf(zs[bb2 * 66 + hh] * scs[hh] + shs[hh], 0.f);
    }
    __syncthreads();
  }

  if (t < BB) {   // agg = max over identical nodes = state itself
    const float* nr = st + t * 66;
    float m = bmu[0], sg = bsig[0];
    #pragma unroll 8
    for (int h = 0; h < 64; h++) {
      float v = nr[h];
      m += v * Wmu[h];
      sg += v * Wsig[h];
    }
    out[t] = m;
    out[BB + t] = sg * sg + 0.01f;
  }
}

// ================================================================ launch
extern "C" void kernel_launch(void* const* d_in, const int* in_sizes, int n_in,
                              void* d_out, int out_size, void* d_ws, size_t ws_size,
                              hipStream_t stream) {
  const float* xx   = (const float*)d_in[0];
  const float* yy   = (const float*)d_in[1];
  const float* oxx  = (const float*)d_in[2];
  const float* W1   = (const float*)d_in[3];
  const float* b1   = (const float*)d_in[4];
  const float* W2   = (const float*)d_in[5];
  const float* b2   = (const float*)d_in[6];
  const float* Wenc = (const float*)d_in[7];
  const float* benc = (const float*)d_in[8];
  // d_in[9]=WQ, [10]=bQ, [15]=wQKq, [17]=bQK, [12]=bK: provably unused
  // (q-side score term constant over softmax axis; bK·wQKk cancels).
  const float* WK   = (const float*)d_in[11];
  const float* WV   = (const float*)d_in[13];
  const float* bV   = (const float*)d_in[14];
  const float* wQKk = (const float*)d_in[16];
  const float* WA   = (const float*)d_in[18];
  const float* bA   = (const float*)d_in[19];
  const float* gamma= (const float*)d_in[20];
  const float* beta = (const float*)d_in[21];
  const float* Wmu  = (const float*)d_in[22];
  const float* bmu  = (const float*)d_in[23];
  const float* Wsig = (const float*)d_in[24];
  const float* bsig = (const float*)d_in[25];

  float* ws  = (float*)d_ws;
  float* out = (float*)d_out;

  k_main<<<NBLK, 256, 0, stream>>>(xx, yy, oxx, W1, b1, W2, b2, Wenc, benc,
                                   WK, wQKk, ws);
  k_tail<<<1, 512, 0, stream>>>(ws, WV, bV, WA, bA, gamma, beta,
                                Wmu, bmu, Wsig, bsig, out);
}